// Round 1
// baseline (191.821 us; speedup 1.0000x reference)
//
#include <hip/hip_runtime.h>
#include <stdint.h>
#include <stddef.h>

typedef _Float16 f16;
typedef f16 f16x4 __attribute__((ext_vector_type(4)));
typedef f16 f16x8 __attribute__((ext_vector_type(8)));
typedef float f32x4 __attribute__((ext_vector_type(4)));

#define DEV __device__ __forceinline__

constexpr int Bb = 4, Nn = 8192, Mm = 2048, C1 = 128, C2 = 256;
constexpr int K0 = 384, CO = 256;

// ---------------------------------------------------------------- async 16B global->LDS
DEV void async16(const void* g, void* l) {
  __builtin_amdgcn_global_load_lds((const __attribute__((address_space(1))) void*)g,
                                   (__attribute__((address_space(3))) void*)l, 16, 0, 0);
}

// ---------------------------------------------------------------- 1) three_nn (np-mimic fp32)
// grid: B*(N/32) blocks of 256. Each block: 32 queries x 8 slices of M.
__global__ __launch_bounds__(256) void knn_kernel(
    const float* __restrict__ unknown, const float* __restrict__ known,
    int* __restrict__ oidx, float* __restrict__ ow)
{
  __shared__ float4 kpts[Mm];        // x,y,z,|k|^2  (32 KB)
  __shared__ float  md[256 * 3];
  __shared__ int    mi[256 * 3];
  const int t  = threadIdx.x;
  const int bx = blockIdx.x;
  const int b  = bx >> 8;            // N/32 = 256 blocks per batch
  const int n0 = (bx & 255) * 32;

  // stage known points + squared norms (np order, no fma)
#pragma unroll
  for (int j = 0; j < 8; ++j) {
    int m = t + j * 256;
    float kx = known[(b * Mm + m) * 3 + 0];
    float ky = known[(b * Mm + m) * 3 + 1];
    float kz = known[(b * Mm + m) * 3 + 2];
    float kk = __fadd_rn(__fadd_rn(__fmul_rn(kx, kx), __fmul_rn(ky, ky)), __fmul_rn(kz, kz));
    kpts[m] = make_float4(kx, ky, kz, kk);
  }
  const int s = t & 7;               // slice: m = it*8 + s
  const int q = n0 + (t >> 3);
  float ux = unknown[(b * Nn + q) * 3 + 0];
  float uy = unknown[(b * Nn + q) * 3 + 1];
  float uz = unknown[(b * Nn + q) * 3 + 2];
  float uu = __fadd_rn(__fadd_rn(__fmul_rn(ux, ux), __fmul_rn(uy, uy)), __fmul_rn(uz, uz));
  __syncthreads();

  float d1 = 1e30f, d2 = 1e30f, d3 = 1e30f;
  int   i1 = 0, i2 = 0, i3 = 0;
  for (int it = 0; it < Mm / 8; ++it) {
    int m = it * 8 + s;              // 8 consecutive m per lane-octet -> conflict-free LDS
    float4 kp = kpts[m];
    float dot = __fadd_rn(__fadd_rn(__fmul_rn(ux, kp.x), __fmul_rn(uy, kp.y)), __fmul_rn(uz, kp.z));
    float dd  = __fadd_rn(__fsub_rn(uu, __fadd_rn(dot, dot)), kp.w); // (uu - 2*dot) + kk
    bool c3 = dd < d3, c2 = dd < d2, c1 = dd < d1;
    d3 = c3 ? (c2 ? d2 : dd) : d3;  i3 = c3 ? (c2 ? i2 : m) : i3;
    d2 = c2 ? (c1 ? d1 : dd) : d2;  i2 = c2 ? (c1 ? i1 : m) : i2;
    d1 = c1 ? dd : d1;              i1 = c1 ? m : i1;
  }
  md[t * 3 + 0] = d1; md[t * 3 + 1] = d2; md[t * 3 + 2] = d3;
  mi[t * 3 + 0] = i1; mi[t * 3 + 1] = i2; mi[t * 3 + 2] = i3;
  __syncthreads();

  if (s == 0) {                      // merge the 8 slices (ties -> lower index, like stable top_k)
    for (int s2 = 1; s2 < 8; ++s2) {
#pragma unroll
      for (int j = 0; j < 3; ++j) {
        float dd = md[(t + s2) * 3 + j]; int m = mi[(t + s2) * 3 + j];
        bool c3 = (dd < d3) || (dd == d3 && m < i3);
        bool c2 = (dd < d2) || (dd == d2 && m < i2);
        bool c1 = (dd < d1) || (dd == d1 && m < i1);
        d3 = c3 ? (c2 ? d2 : dd) : d3;  i3 = c3 ? (c2 ? i2 : m) : i3;
        d2 = c2 ? (c1 ? d1 : dd) : d2;  i2 = c2 ? (c1 ? i1 : m) : i2;
        d1 = c1 ? dd : d1;              i1 = c1 ? m : i1;
      }
    }
    float t1 = sqrtf(fmaxf(d1, 0.f)), t2 = sqrtf(fmaxf(d2, 0.f)), t3 = sqrtf(fmaxf(d3, 0.f));
    float r1 = 1.f / (t1 + 1e-8f), r2 = 1.f / (t2 + 1e-8f), r3 = 1.f / (t3 + 1e-8f);
    float rs = __fadd_rn(__fadd_rn(r1, r2), r3);
    int base = (b * Nn + q) * 3;
    oidx[base + 0] = i1; oidx[base + 1] = i2; oidx[base + 2] = i3;
    ow[base + 0] = r1 / rs; ow[base + 1] = r2 / rs; ow[base + 2] = r3 / rs;
  }
}

// ---------------------------------------------------------------- 2) known_feats (B,C2,M) f32 -> kfT (B,M,C2) f16
__global__ __launch_bounds__(256) void kft_kernel(const float* __restrict__ kf, f16* __restrict__ kfT)
{
  __shared__ f16 tile[64][72];
  const int t = threadIdx.x;
  const int m0 = blockIdx.x * 64, c0 = blockIdx.y * 64, b = blockIdx.z;
  const int lm = t & 63, row = t >> 6;
#pragma unroll
  for (int j = 0; j < 16; ++j) {
    int c = row + j * 4;
    tile[lm][c] = (f16)kf[(size_t)(b * C2 + c0 + c) * Mm + m0 + lm];
  }
  __syncthreads();
#pragma unroll
  for (int j = 0; j < 16; ++j) {
    int m = row + j * 4;
    kfT[(size_t)(b * Mm + m0 + m) * C2 + c0 + lm] = tile[m][lm];
  }
}

// ---------------------------------------------------------------- 3) weight fp32->fp16
__global__ void wcvt_kernel(const float* __restrict__ W0, const float* __restrict__ W1,
                            f16* __restrict__ Wh0, f16* __restrict__ Wh1)
{
  int i = blockIdx.x * 256 + threadIdx.x;
  if (i < CO * K0) Wh0[i] = (f16)W0[i];
  if (i < CO * CO) Wh1[i] = (f16)W1[i];
}

// ---------------------------------------------------------------- 4) three_interpolate -> x0[b][n][0..255] (f16, K-fast)
__global__ __launch_bounds__(256) void interp_kernel(
    const f16* __restrict__ kfT, const int* __restrict__ idx, const float* __restrict__ wts,
    f16* __restrict__ x0)
{
  const int t = threadIdx.x;
  const int wv = t >> 6, l = t & 63;
  const int b = blockIdx.y;
  const int n0 = blockIdx.x * 64;
  for (int it = 0; it < 16; ++it) {
    int q = n0 + it * 4 + wv;                 // wave-uniform -> scalar idx/weight loads
    int base = (b * Nn + q) * 3;
    int i0 = idx[base + 0], i1 = idx[base + 1], i2 = idx[base + 2];
    float w0 = wts[base + 0], w1 = wts[base + 1], w2 = wts[base + 2];
    const f16x4* r0 = (const f16x4*)(kfT + (size_t)(b * Mm + i0) * C2);
    const f16x4* r1 = (const f16x4*)(kfT + (size_t)(b * Mm + i1) * C2);
    const f16x4* r2 = (const f16x4*)(kfT + (size_t)(b * Mm + i2) * C2);
    f16x4 a0 = r0[l], a1 = r1[l], a2 = r2[l];
    f16x4 o;
#pragma unroll
    for (int j = 0; j < 4; ++j) {
      float v = w0 * (float)a0[j] + w1 * (float)a1[j] + w2 * (float)a2[j];
      o[j] = (f16)v;
    }
    *(f16x4*)(x0 + (size_t)(b * Nn + q) * K0 + l * 4) = o;
  }
}

// ---------------------------------------------------------------- 5) unknow_feats (B,C1,N) f32 -> x0[b][n][256..383] f16
__global__ __launch_bounds__(256) void uft_kernel(const float* __restrict__ uf, f16* __restrict__ x0)
{
  __shared__ f16 tile[64][136];
  const int t = threadIdx.x;
  const int b = blockIdx.y;
  const int n0 = blockIdx.x * 64;
  const int ln = t & 63, cr = t >> 6;
#pragma unroll
  for (int j = 0; j < 32; ++j) {
    int c = j * 4 + cr;
    tile[ln][c] = (f16)uf[(size_t)(b * C1 + c) * Nn + n0 + ln];
  }
  __syncthreads();
  const int ch = t & 15, rr = t >> 4;
#pragma unroll
  for (int j = 0; j < 4; ++j) {
    int n = j * 16 + rr;
    f16x8 v = *(const f16x8*)&tile[n][ch * 8];
    *(f16x8*)(x0 + (size_t)(b * Nn + n0 + n) * K0 + C2 + ch * 8) = v;
  }
}

// ---------------------------------------------------------------- 6) fp16 MFMA GEMM + BN + ReLU
// C[m][n] = sum_k A[m][k] * X[b][n][k];  128x128 tile, BK=32, 2x2 waves, 16x16x32 MFMA.
// LDS tiles hold 16B k-octets with XOR swizzle p = row*4 + (q ^ ((row>>1)&3)) so that
// linear global_load_lds staging AND conflict-free ds_read_b128 fragment reads coexist.
template<int KD, bool TRANS>
__global__ __launch_bounds__(256) void gemm_kernel(
    const f16* __restrict__ A, const f16* __restrict__ X,
    const float* __restrict__ bias, const float* __restrict__ gam,
    const float* __restrict__ bet, const float* __restrict__ rmean,
    const float* __restrict__ rvar,
    f16* __restrict__ outT,     // TRANS:  (B,N,256) f16 (layer-0 -> layer-1 input)
    float* __restrict__ outF)   // !TRANS: (B,256,N) f32 (final output)
{
  constexpr int STAGE = 16384;                       // A 8KB + B 8KB
  constexpr int TB = TRANS ? (128 * 136 * 2) : STAGE;
  constexpr int BNOFF = (TB > STAGE ? TB : STAGE);
  __shared__ __align__(16) char lds[BNOFF + 1024];

  const int t = threadIdx.x;
  const int w = t >> 6, l = t & 63;
  const int n0 = blockIdx.x * 128;
  const int m0 = blockIdx.y * 128;
  const int b  = blockIdx.z;

  float* bnS = (float*)(lds + BNOFF);
  float* bnH = bnS + 128;
  if (t < 128) {
    int c = m0 + t;
    float sc = gam[c] / sqrtf(rvar[c] + 1e-5f);
    bnS[t] = sc;
    bnH[t] = (bias[c] - rmean[c]) * sc + bet[c];
  }

  // staging: slot s = call*256 + t; row = s>>2, stored octet q = (s&3) ^ ((row>>1)&3)
  const int sa = t, sb = 256 + t;
  const int ra = sa >> 2, qa = (sa & 3) ^ ((ra >> 1) & 3);
  const int rb = sb >> 2, qb = (sb & 3) ^ ((rb >> 1) & 3);
  const f16* gA0 = A + (size_t)(m0 + ra) * KD + qa * 8;
  const f16* gA1 = A + (size_t)(m0 + rb) * KD + qb * 8;
  const f16* gB0 = X + (size_t)(b * Nn + n0 + ra) * KD + qa * 8;
  const f16* gB1 = X + (size_t)(b * Nn + n0 + rb) * KD + qb * 8;
  char* lA0 = lds + w * 1024;
  char* lA1 = lds + 4096 + w * 1024;
  char* lB0 = lds + 8192 + w * 1024;
  char* lB1 = lds + 8192 + 4096 + w * 1024;

  const int lm = l & 15, qq = l >> 4;
  int offA[4], offB[4];
#pragma unroll
  for (int i = 0; i < 4; ++i) {
    int m = (w >> 1) * 64 + i * 16 + lm;
    offA[i] = (m * 4 + (qq ^ ((m >> 1) & 3))) * 16;
    int n = (w & 1) * 64 + i * 16 + lm;
    offB[i] = 8192 + (n * 4 + (qq ^ ((n >> 1) & 3))) * 16;
  }

  f32x4 acc[4][4] = {};
  for (int k0 = 0; k0 < KD; k0 += 32) {
    __syncthreads();                         // LDS free to overwrite
    async16(gA0, lA0); async16(gA1, lA1);
    async16(gB0, lB0); async16(gB1, lB1);
    __syncthreads();                         // vmcnt(0) drained by compiler before barrier
    gA0 += 32; gA1 += 32; gB0 += 32; gB1 += 32;
    f16x8 af[4], bf[4];
#pragma unroll
    for (int i = 0; i < 4; ++i) {
      af[i] = *(const f16x8*)(lds + offA[i]);
      bf[i] = *(const f16x8*)(lds + offB[i]);
    }
#pragma unroll
    for (int i = 0; i < 4; ++i)
#pragma unroll
      for (int j = 0; j < 4; ++j)
        acc[i][j] = __builtin_amdgcn_mfma_f32_16x16x32_f16(af[i], bf[j], acc[i][j], 0, 0, 0);
  }

  const int wm = (w >> 1) * 64, wn = (w & 1) * 64;
  if constexpr (TRANS) {
    __syncthreads();                         // all frag reads done before LDS reuse
    f16* T = (f16*)lds;                      // [128 n][136 m-pitch]
#pragma unroll
    for (int i = 0; i < 4; ++i) {
      int mb = wm + i * 16 + qq * 4;
      float s0v = bnS[mb + 0], s1v = bnS[mb + 1], s2v = bnS[mb + 2], s3v = bnS[mb + 3];
      float h0v = bnH[mb + 0], h1v = bnH[mb + 1], h2v = bnH[mb + 2], h3v = bnH[mb + 3];
#pragma unroll
      for (int j = 0; j < 4; ++j) {
        int n = wn + j * 16 + lm;
        f16x4 v;
        v[0] = (f16)fmaxf(fmaf(acc[i][j][0], s0v, h0v), 0.f);
        v[1] = (f16)fmaxf(fmaf(acc[i][j][1], s1v, h1v), 0.f);
        v[2] = (f16)fmaxf(fmaf(acc[i][j][2], s2v, h2v), 0.f);
        v[3] = (f16)fmaxf(fmaf(acc[i][j][3], s3v, h3v), 0.f);
        *(f16x4*)&T[n * 136 + mb] = v;
      }
    }
    __syncthreads();
    const int ch = t & 15, rr = t >> 4;
#pragma unroll
    for (int j = 0; j < 8; ++j) {
      int n = j * 16 + rr;
      f16x8 v = *(const f16x8*)&T[n * 136 + ch * 8];
      *(f16x8*)(outT + (size_t)(b * Nn + n0 + n) * CO + m0 + ch * 8) = v;
    }
  } else {
#pragma unroll
    for (int i = 0; i < 4; ++i) {
#pragma unroll
      for (int r = 0; r < 4; ++r) {
        int ml = wm + i * 16 + qq * 4 + r;
        float sc = bnS[ml], sh = bnH[ml];
#pragma unroll
        for (int j = 0; j < 4; ++j) {
          int n = wn + j * 16 + lm;
          float y = fmaxf(fmaf(acc[i][j][r], sc, sh), 0.f);
          outF[(size_t)(b * CO + m0 + ml) * Nn + n0 + n] = y;
        }
      }
    }
  }
}

// ---------------------------------------------------------------- launch
extern "C" void kernel_launch(void* const* d_in, const int* in_sizes, int n_in,
                              void* d_out, int out_size, void* d_ws, size_t ws_size,
                              hipStream_t stream)
{
  const float* unknown = (const float*)d_in[0];
  const float* known   = (const float*)d_in[1];
  const float* uf      = (const float*)d_in[2];
  const float* kf      = (const float*)d_in[3];
  const float* W0  = (const float*)d_in[4];
  const float* b0  = (const float*)d_in[5];
  const float* g0  = (const float*)d_in[6];
  const float* be0 = (const float*)d_in[7];
  const float* rm0 = (const float*)d_in[8];
  const float* rv0 = (const float*)d_in[9];
  const float* W1  = (const float*)d_in[10];
  const float* b1  = (const float*)d_in[11];
  const float* g1  = (const float*)d_in[12];
  const float* be1 = (const float*)d_in[13];
  const float* rm1 = (const float*)d_in[14];
  const float* rv1 = (const float*)d_in[15];

  char* ws = (char*)d_ws;
  // ws layout (bytes, all 256-aligned): total ~47.3 MB
  int*   idx = (int*)  (ws + 0);          // B*N*3 i32   = 384 KB
  float* wts = (float*)(ws + 393216);     // B*N*3 f32   = 384 KB
  f16*   kfT = (f16*)  (ws + 786432);     // B*M*C2 f16  = 4 MB
  f16*   Wh0 = (f16*)  (ws + 4980736);    // 256*384 f16
  f16*   Wh1 = (f16*)  (ws + 5177344);    // 256*256 f16
  f16*   x0  = (f16*)  (ws + 5308416);    // B*N*384 f16 = 25.2 MB
  f16*   x1  = (f16*)  (ws + 30474240);   // B*N*256 f16 = 16.8 MB
  float* out = (float*)d_out;             // (B,256,N) f32

  knn_kernel   <<<dim3(Bb * (Nn / 32)), 256, 0, stream>>>(unknown, known, idx, wts);
  kft_kernel   <<<dim3(Mm / 64, C2 / 64, Bb), 256, 0, stream>>>(kf, kfT);
  wcvt_kernel  <<<dim3((CO * K0 + 255) / 256), 256, 0, stream>>>(W0, W1, Wh0, Wh1);
  interp_kernel<<<dim3(Nn / 64, Bb), 256, 0, stream>>>(kfT, idx, wts, x0);
  uft_kernel   <<<dim3(Nn / 64, Bb), 256, 0, stream>>>(uf, x0);
  gemm_kernel<K0, true> <<<dim3(Nn / 128, 2, Bb), 256, 0, stream>>>(Wh0, x0, b0, g0, be0, rm0, rv0, x1, nullptr);
  gemm_kernel<CO, false><<<dim3(Nn / 128, 2, Bb), 256, 0, stream>>>(Wh1, x1, b1, g1, be1, rm1, rv1, nullptr, out);
}

// Round 2
// 185.775 us; speedup vs baseline: 1.0325x; 1.0325x over previous
//
#include <hip/hip_runtime.h>
#include <stdint.h>
#include <stddef.h>

typedef _Float16 f16;
typedef f16 f16x4 __attribute__((ext_vector_type(4)));
typedef f16 f16x8 __attribute__((ext_vector_type(8)));
typedef float f32x4 __attribute__((ext_vector_type(4)));

#define DEV __device__ __forceinline__

constexpr int Bb = 4, Nn = 8192, Mm = 2048, C1 = 128, C2 = 256;
constexpr int K0 = 384, CO = 256;

// ---------------------------------------------------------------- async 16B global->LDS
DEV void async16(const void* g, void* l) {
  __builtin_amdgcn_global_load_lds((const __attribute__((address_space(1))) void*)g,
                                   (__attribute__((address_space(3))) void*)l, 16, 0, 0);
}

// ---------------------------------------------------------------- 1) three_nn (np-mimic fp32)
// 16-way M-slicing: grid B*(N/16) blocks of 256; each block: 16 queries x 16 slices.
// Scan: min/med3 distance maintenance (3 ops) + cndmask index tracking (5 ops).
// Merge: 4-step shfl_xor butterfly within each 16-lane slice group (no LDS, no serial tail).
__global__ __launch_bounds__(256) void knn_kernel(
    const float* __restrict__ unknown, const float* __restrict__ known,
    int* __restrict__ oidx, float* __restrict__ ow)
{
  __shared__ float4 kpts[Mm];        // x,y,z,|k|^2  (32 KB -> 5 blocks/CU)
  const int t  = threadIdx.x;
  const int bx = blockIdx.x;
  const int b  = bx >> 9;            // N/16 = 512 blocks per batch
  const int n0 = (bx & 511) * 16;

  // stage known points + squared norms (np order, no fma)
#pragma unroll
  for (int j = 0; j < 8; ++j) {
    int m = t + j * 256;
    float kx = known[(b * Mm + m) * 3 + 0];
    float ky = known[(b * Mm + m) * 3 + 1];
    float kz = known[(b * Mm + m) * 3 + 2];
    float kk = __fadd_rn(__fadd_rn(__fmul_rn(kx, kx), __fmul_rn(ky, ky)), __fmul_rn(kz, kz));
    kpts[m] = make_float4(kx, ky, kz, kk);
  }
  const int s = t & 15;              // slice: m = it*16 + s
  const int q = n0 + (t >> 4);
  float ux = unknown[(b * Nn + q) * 3 + 0];
  float uy = unknown[(b * Nn + q) * 3 + 1];
  float uz = unknown[(b * Nn + q) * 3 + 2];
  float uu = __fadd_rn(__fadd_rn(__fmul_rn(ux, ux), __fmul_rn(uy, uy)), __fmul_rn(uz, uz));
  __syncthreads();

  float d1 = 1e30f, d2 = 1e30f, d3 = 1e30f;
  int   i1 = 0, i2 = 0, i3 = 0;
#pragma unroll 4
  for (int it = 0; it < Mm / 16; ++it) {
    int m = it * 16 + s;
    float4 kp = kpts[m];
    float dot = __fadd_rn(__fadd_rn(__fmul_rn(ux, kp.x), __fmul_rn(uy, kp.y)), __fmul_rn(uz, kp.z));
    float dd  = __fadd_rn(__fsub_rn(uu, __fadd_rn(dot, dot)), kp.w); // (uu - 2*dot) + kk
    bool c1 = dd < d1, c2 = dd < d2, c3 = dd < d3;
    i3 = c3 ? (c2 ? i2 : m) : i3;
    i2 = c2 ? (c1 ? i1 : m) : i2;
    i1 = c1 ? m : i1;
    d3 = __builtin_amdgcn_fmed3f(dd, d2, d3);   // new top-3 distances: min + 2x med3
    d2 = __builtin_amdgcn_fmed3f(dd, d1, d2);
    d1 = fminf(dd, d1);
  }

  // butterfly merge across the 16 slices (ties -> lower index, like stable top_k)
#pragma unroll
  for (int mask = 1; mask <= 8; mask <<= 1) {
    float e1 = __shfl_xor(d1, mask), e2 = __shfl_xor(d2, mask), e3 = __shfl_xor(d3, mask);
    int   j1 = __shfl_xor(i1, mask), j2 = __shfl_xor(i2, mask), j3 = __shfl_xor(i3, mask);
#pragma unroll
    for (int u = 0; u < 3; ++u) {
      float e = u == 0 ? e1 : (u == 1 ? e2 : e3);
      int   j = u == 0 ? j1 : (u == 1 ? j2 : j3);
      bool c3 = (e < d3) || (e == d3 && j < i3);
      bool c2 = (e < d2) || (e == d2 && j < i2);
      bool c1 = (e < d1) || (e == d1 && j < i1);
      d3 = c3 ? (c2 ? d2 : e) : d3;  i3 = c3 ? (c2 ? i2 : j) : i3;
      d2 = c2 ? (c1 ? d1 : e) : d2;  i2 = c2 ? (c1 ? i1 : j) : i2;
      d1 = c1 ? e : d1;              i1 = c1 ? j : i1;
    }
  }

  if (s == 0) {
    float t1 = sqrtf(fmaxf(d1, 0.f)), t2 = sqrtf(fmaxf(d2, 0.f)), t3 = sqrtf(fmaxf(d3, 0.f));
    float r1 = 1.f / (t1 + 1e-8f), r2 = 1.f / (t2 + 1e-8f), r3 = 1.f / (t3 + 1e-8f);
    float rs = __fadd_rn(__fadd_rn(r1, r2), r3);
    int base = (b * Nn + q) * 3;
    oidx[base + 0] = i1; oidx[base + 1] = i2; oidx[base + 2] = i3;
    ow[base + 0] = r1 / rs; ow[base + 1] = r2 / rs; ow[base + 2] = r3 / rs;
  }
}

// ---------------------------------------------------------------- 2) known_feats (B,C2,M) f32 -> kfT (B,M,C2) f16
__global__ __launch_bounds__(256) void kft_kernel(const float* __restrict__ kf, f16* __restrict__ kfT)
{
  __shared__ f16 tile[64][72];
  const int t = threadIdx.x;
  const int m0 = blockIdx.x * 64, c0 = blockIdx.y * 64, b = blockIdx.z;
  const int lm = t & 63, row = t >> 6;
#pragma unroll
  for (int j = 0; j < 16; ++j) {
    int c = row + j * 4;
    tile[lm][c] = (f16)kf[(size_t)(b * C2 + c0 + c) * Mm + m0 + lm];
  }
  __syncthreads();
#pragma unroll
  for (int j = 0; j < 16; ++j) {
    int m = row + j * 4;
    kfT[(size_t)(b * Mm + m0 + m) * C2 + c0 + lm] = tile[m][lm];
  }
}

// ---------------------------------------------------------------- 3) weight fp32->fp16
__global__ void wcvt_kernel(const float* __restrict__ W0, const float* __restrict__ W1,
                            f16* __restrict__ Wh0, f16* __restrict__ Wh1)
{
  int i = blockIdx.x * 256 + threadIdx.x;
  if (i < CO * K0) Wh0[i] = (f16)W0[i];
  if (i < CO * CO) Wh1[i] = (f16)W1[i];
}

// ---------------------------------------------------------------- 4) three_interpolate -> x0[b][n][0..255] (f16, K-fast)
__global__ __launch_bounds__(256) void interp_kernel(
    const f16* __restrict__ kfT, const int* __restrict__ idx, const float* __restrict__ wts,
    f16* __restrict__ x0)
{
  const int t = threadIdx.x;
  const int wv = t >> 6, l = t & 63;
  const int b = blockIdx.y;
  const int n0 = blockIdx.x * 64;
  for (int it = 0; it < 16; ++it) {
    int q = n0 + it * 4 + wv;                 // wave-uniform -> scalar idx/weight loads
    int base = (b * Nn + q) * 3;
    int i0 = idx[base + 0], i1 = idx[base + 1], i2 = idx[base + 2];
    float w0 = wts[base + 0], w1 = wts[base + 1], w2 = wts[base + 2];
    const f16x4* r0 = (const f16x4*)(kfT + (size_t)(b * Mm + i0) * C2);
    const f16x4* r1 = (const f16x4*)(kfT + (size_t)(b * Mm + i1) * C2);
    const f16x4* r2 = (const f16x4*)(kfT + (size_t)(b * Mm + i2) * C2);
    f16x4 a0 = r0[l], a1 = r1[l], a2 = r2[l];
    f16x4 o;
#pragma unroll
    for (int j = 0; j < 4; ++j) {
      float v = w0 * (float)a0[j] + w1 * (float)a1[j] + w2 * (float)a2[j];
      o[j] = (f16)v;
    }
    *(f16x4*)(x0 + (size_t)(b * Nn + q) * K0 + l * 4) = o;
  }
}

// ---------------------------------------------------------------- 5) unknow_feats (B,C1,N) f32 -> x0[b][n][256..383] f16
__global__ __launch_bounds__(256) void uft_kernel(const float* __restrict__ uf, f16* __restrict__ x0)
{
  __shared__ f16 tile[64][136];
  const int t = threadIdx.x;
  const int b = blockIdx.y;
  const int n0 = blockIdx.x * 64;
  const int ln = t & 63, cr = t >> 6;
#pragma unroll
  for (int j = 0; j < 32; ++j) {
    int c = j * 4 + cr;
    tile[ln][c] = (f16)uf[(size_t)(b * C1 + c) * Nn + n0 + ln];
  }
  __syncthreads();
  const int ch = t & 15, rr = t >> 4;
#pragma unroll
  for (int j = 0; j < 4; ++j) {
    int n = j * 16 + rr;
    f16x8 v = *(const f16x8*)&tile[n][ch * 8];
    *(f16x8*)(x0 + (size_t)(b * Nn + n0 + n) * K0 + C2 + ch * 8) = v;
  }
}

// ---------------------------------------------------------------- 6) fp16 MFMA GEMM + BN + ReLU
// C[m][n] = sum_k A[m][k] * X[b][n][k];  128x128 tile, BK=32, 2x2 waves, 16x16x32 MFMA.
// LDS tiles hold 16B k-octets with XOR swizzle p = row*4 + (q ^ ((row>>1)&3)) so that
// linear global_load_lds staging AND conflict-free ds_read_b128 fragment reads coexist.
template<int KD, bool TRANS>
__global__ __launch_bounds__(256) void gemm_kernel(
    const f16* __restrict__ A, const f16* __restrict__ X,
    const float* __restrict__ bias, const float* __restrict__ gam,
    const float* __restrict__ bet, const float* __restrict__ rmean,
    const float* __restrict__ rvar,
    f16* __restrict__ outT,     // TRANS:  (B,N,256) f16 (layer-0 -> layer-1 input)
    float* __restrict__ outF)   // !TRANS: (B,256,N) f32 (final output)
{
  constexpr int STAGE = 16384;                       // A 8KB + B 8KB
  constexpr int TB = TRANS ? (128 * 136 * 2) : STAGE;
  constexpr int BNOFF = (TB > STAGE ? TB : STAGE);
  __shared__ __align__(16) char lds[BNOFF + 1024];

  const int t = threadIdx.x;
  const int w = t >> 6, l = t & 63;
  const int n0 = blockIdx.x * 128;
  const int m0 = blockIdx.y * 128;
  const int b  = blockIdx.z;

  float* bnS = (float*)(lds + BNOFF);
  float* bnH = bnS + 128;
  if (t < 128) {
    int c = m0 + t;
    float sc = gam[c] / sqrtf(rvar[c] + 1e-5f);
    bnS[t] = sc;
    bnH[t] = (bias[c] - rmean[c]) * sc + bet[c];
  }

  // staging: slot s = call*256 + t; row = s>>2, stored octet q = (s&3) ^ ((row>>1)&3)
  const int sa = t, sb = 256 + t;
  const int ra = sa >> 2, qa = (sa & 3) ^ ((ra >> 1) & 3);
  const int rb = sb >> 2, qb = (sb & 3) ^ ((rb >> 1) & 3);
  const f16* gA0 = A + (size_t)(m0 + ra) * KD + qa * 8;
  const f16* gA1 = A + (size_t)(m0 + rb) * KD + qb * 8;
  const f16* gB0 = X + (size_t)(b * Nn + n0 + ra) * KD + qa * 8;
  const f16* gB1 = X + (size_t)(b * Nn + n0 + rb) * KD + qb * 8;
  char* lA0 = lds + w * 1024;
  char* lA1 = lds + 4096 + w * 1024;
  char* lB0 = lds + 8192 + w * 1024;
  char* lB1 = lds + 8192 + 4096 + w * 1024;

  const int lm = l & 15, qq = l >> 4;
  int offA[4], offB[4];
#pragma unroll
  for (int i = 0; i < 4; ++i) {
    int m = (w >> 1) * 64 + i * 16 + lm;
    offA[i] = (m * 4 + (qq ^ ((m >> 1) & 3))) * 16;
    int n = (w & 1) * 64 + i * 16 + lm;
    offB[i] = 8192 + (n * 4 + (qq ^ ((n >> 1) & 3))) * 16;
  }

  f32x4 acc[4][4] = {};
  for (int k0 = 0; k0 < KD; k0 += 32) {
    __syncthreads();                         // LDS free to overwrite
    async16(gA0, lA0); async16(gA1, lA1);
    async16(gB0, lB0); async16(gB1, lB1);
    __syncthreads();                         // vmcnt(0) drained by compiler before barrier
    gA0 += 32; gA1 += 32; gB0 += 32; gB1 += 32;
    f16x8 af[4], bf[4];
#pragma unroll
    for (int i = 0; i < 4; ++i) {
      af[i] = *(const f16x8*)(lds + offA[i]);
      bf[i] = *(const f16x8*)(lds + offB[i]);
    }
#pragma unroll
    for (int i = 0; i < 4; ++i)
#pragma unroll
      for (int j = 0; j < 4; ++j)
        acc[i][j] = __builtin_amdgcn_mfma_f32_16x16x32_f16(af[i], bf[j], acc[i][j], 0, 0, 0);
  }

  const int wm = (w >> 1) * 64, wn = (w & 1) * 64;
  if constexpr (TRANS) {
    __syncthreads();                         // all frag reads done before LDS reuse
    f16* T = (f16*)lds;                      // [128 n][136 m-pitch]
#pragma unroll
    for (int i = 0; i < 4; ++i) {
      int mb = wm + i * 16 + qq * 4;
      float s0v = bnS[mb + 0], s1v = bnS[mb + 1], s2v = bnS[mb + 2], s3v = bnS[mb + 3];
      float h0v = bnH[mb + 0], h1v = bnH[mb + 1], h2v = bnH[mb + 2], h3v = bnH[mb + 3];
#pragma unroll
      for (int j = 0; j < 4; ++j) {
        int n = wn + j * 16 + lm;
        f16x4 v;
        v[0] = (f16)fmaxf(fmaf(acc[i][j][0], s0v, h0v), 0.f);
        v[1] = (f16)fmaxf(fmaf(acc[i][j][1], s1v, h1v), 0.f);
        v[2] = (f16)fmaxf(fmaf(acc[i][j][2], s2v, h2v), 0.f);
        v[3] = (f16)fmaxf(fmaf(acc[i][j][3], s3v, h3v), 0.f);
        *(f16x4*)&T[n * 136 + mb] = v;
      }
    }
    __syncthreads();
    const int ch = t & 15, rr = t >> 4;
#pragma unroll
    for (int j = 0; j < 8; ++j) {
      int n = j * 16 + rr;
      f16x8 v = *(const f16x8*)&T[n * 136 + ch * 8];
      *(f16x8*)(outT + (size_t)(b * Nn + n0 + n) * CO + m0 + ch * 8) = v;
    }
  } else {
#pragma unroll
    for (int i = 0; i < 4; ++i) {
#pragma unroll
      for (int r = 0; r < 4; ++r) {
        int ml = wm + i * 16 + qq * 4 + r;
        float sc = bnS[ml], sh = bnH[ml];
#pragma unroll
        for (int j = 0; j < 4; ++j) {
          int n = wn + j * 16 + lm;
          float y = fmaxf(fmaf(acc[i][j][r], sc, sh), 0.f);
          outF[(size_t)(b * CO + m0 + ml) * Nn + n0 + n] = y;
        }
      }
    }
  }
}

// ---------------------------------------------------------------- launch
extern "C" void kernel_launch(void* const* d_in, const int* in_sizes, int n_in,
                              void* d_out, int out_size, void* d_ws, size_t ws_size,
                              hipStream_t stream)
{
  const float* unknown = (const float*)d_in[0];
  const float* known   = (const float*)d_in[1];
  const float* uf      = (const float*)d_in[2];
  const float* kf      = (const float*)d_in[3];
  const float* W0  = (const float*)d_in[4];
  const float* b0  = (const float*)d_in[5];
  const float* g0  = (const float*)d_in[6];
  const float* be0 = (const float*)d_in[7];
  const float* rm0 = (const float*)d_in[8];
  const float* rv0 = (const float*)d_in[9];
  const float* W1  = (const float*)d_in[10];
  const float* b1  = (const float*)d_in[11];
  const float* g1  = (const float*)d_in[12];
  const float* be1 = (const float*)d_in[13];
  const float* rm1 = (const float*)d_in[14];
  const float* rv1 = (const float*)d_in[15];

  char* ws = (char*)d_ws;
  // ws layout (bytes, all 256-aligned): total ~47.3 MB
  int*   idx = (int*)  (ws + 0);          // B*N*3 i32   = 384 KB
  float* wts = (float*)(ws + 393216);     // B*N*3 f32   = 384 KB
  f16*   kfT = (f16*)  (ws + 786432);     // B*M*C2 f16  = 4 MB
  f16*   Wh0 = (f16*)  (ws + 4980736);    // 256*384 f16
  f16*   Wh1 = (f16*)  (ws + 5177344);    // 256*256 f16
  f16*   x0  = (f16*)  (ws + 5308416);    // B*N*384 f16 = 25.2 MB
  f16*   x1  = (f16*)  (ws + 30474240);   // B*N*256 f16 = 16.8 MB
  float* out = (float*)d_out;             // (B,256,N) f32

  knn_kernel   <<<dim3(Bb * (Nn / 16)), 256, 0, stream>>>(unknown, known, idx, wts);
  kft_kernel   <<<dim3(Mm / 64, C2 / 64, Bb), 256, 0, stream>>>(kf, kfT);
  wcvt_kernel  <<<dim3((CO * K0 + 255) / 256), 256, 0, stream>>>(W0, W1, Wh0, Wh1);
  interp_kernel<<<dim3(Nn / 64, Bb), 256, 0, stream>>>(kfT, idx, wts, x0);
  uft_kernel   <<<dim3(Nn / 64, Bb), 256, 0, stream>>>(uf, x0);
  gemm_kernel<K0, true> <<<dim3(Nn / 128, 2, Bb), 256, 0, stream>>>(Wh0, x0, b0, g0, be0, rm0, rv0, x1, nullptr);
  gemm_kernel<CO, false><<<dim3(Nn / 128, 2, Bb), 256, 0, stream>>>(Wh1, x1, b1, g1, be1, rm1, rv1, nullptr, out);
}